// Round 9
// baseline (443.379 us; speedup 1.0000x reference)
//
#include <hip/hip_runtime.h>
#include <math.h>

#define SCALEF 0.25f   // 1/sqrt(D=16)

typedef __attribute__((ext_vector_type(8))) short short8;
typedef __attribute__((ext_vector_type(4))) float f32x4;

__device__ __forceinline__ unsigned short f2bf(float x) {
  unsigned u = __float_as_uint(x);
  unsigned r = u + 0x7FFFu + ((u >> 16) & 1u);
  return (unsigned short)(r >> 16);
}
__device__ __forceinline__ float bf2f(unsigned short h) {
  return __uint_as_float(((unsigned)h) << 16);
}

// ======================= CSR build =======================
__global__ void k_hist(const int* __restrict__ dst, int* __restrict__ counts, int E) {
  int i = blockIdx.x * 256 + threadIdx.x;
  if (i < E) atomicAdd(&counts[dst[i]], 1);
}

__global__ __launch_bounds__(1024) void k_scan1(const int* __restrict__ counts,
                                                int* __restrict__ excl,
                                                int* __restrict__ bsums, int n) {
  __shared__ int sd[1024];
  int t = threadIdx.x;
  int i = blockIdx.x * 1024 + t;
  int v = (i < n) ? counts[i] : 0;
  sd[t] = v;
  __syncthreads();
  for (int off = 1; off < 1024; off <<= 1) {
    int x = (t >= off) ? sd[t - off] : 0;
    __syncthreads();
    sd[t] += x;
    __syncthreads();
  }
  if (i < n) excl[i] = sd[t] - v;
  if (t == 1023) bsums[blockIdx.x] = sd[1023];
}

__global__ void k_scan2(int* bsums, int nb) {
  if (threadIdx.x == 0 && blockIdx.x == 0) {
    int run = 0;
    for (int i = 0; i < nb; ++i) { int v = bsums[i]; bsums[i] = run; run += v; }
  }
}

__global__ __launch_bounds__(1024) void k_scan3(int* __restrict__ rowptr, int* __restrict__ cursor,
                                                const int* __restrict__ bsums, int n, int Etot) {
  int i = blockIdx.x * 1024 + threadIdx.x;
  if (i < n) { int v = rowptr[i] + bsums[blockIdx.x]; rowptr[i] = v; cursor[i] = v; }
  if (i == 0) rowptr[n] = Etot;
}

__global__ void k_scatter(const int* __restrict__ dst, int* __restrict__ cursor,
                          int* __restrict__ colidx, int E) {
  int i = blockIdx.x * 256 + threadIdx.x;
  if (i < E) { int pos = atomicAdd(&cursor[dst[i]], 1); colidx[pos] = i; }
}

// permute esrc + edge_attr into CSR order. esrcp holds BYTE offsets into the
// bf16 K/V arrays (sn*128); EAp stays f32 (one 64B line per edge in attn).
__global__ void k_perm(const int* __restrict__ colidx, const int* __restrict__ esrc,
                       const float* __restrict__ EA, int* __restrict__ esrcp,
                       float* __restrict__ EAp, int E) {
  int r = blockIdx.x * 256 + threadIdx.x;
  if (r >= E) return;
  const int eid = colidx[r];
  esrcp[r] = esrc[eid] * 128;
  const float4* s4 = (const float4*)(EA + ((size_t)eid << 4));
  float4* d4 = (float4*)(EAp + ((size_t)r << 4));
  d4[0] = s4[0]; d4[1] = s4[1]; d4[2] = s4[2]; d4[3] = s4[3];
}

// ======================= per-layer Wqt = (Wq @ M)*SCALE =======================
__global__ __launch_bounds__(256) void k_wqt(
    const float* __restrict__ Wq0, const float* __restrict__ bq0, const float* __restrict__ We0,
    const float* __restrict__ Wq, const float* __restrict__ bq, const float* __restrict__ We,
    float* __restrict__ Wqt, float* __restrict__ bqt) {
  const int l = blockIdx.x;
  const float* wq = (l == 0) ? Wq0 : Wq + (l - 1) * 4096;
  const float* bv = (l == 0) ? bq0 : bq + (l - 1) * 64;
  const float* we = (l == 0) ? We0 : We + (l - 1) * 1024;
  float* out  = Wqt + l * 4096;
  float* outb = bqt + l * 64;
  const int t = threadIdx.x;
  const int r = t >> 2;
  const int hh = t & 3;
  float wqr[16];
  #pragma unroll
  for (int d = 0; d < 16; ++d) wqr[d] = wq[r * 64 + hh * 16 + d];
  #pragma unroll
  for (int bb = 0; bb < 16; ++bb) {
    float s = 0.f;
    #pragma unroll
    for (int d = 0; d < 16; ++d) s += wqr[d] * we[bb * 64 + hh * 16 + d];
    out[r * 64 + hh * 16 + bb] = s * SCALEF;
  }
  if (r == 0) {
    #pragma unroll
    for (int bb = 0; bb < 16; ++bb) {
      float s = 0.f;
      #pragma unroll
      for (int d = 0; d < 16; ++d) s += bv[hh * 16 + d] * we[bb * 64 + hh * 16 + d];
      outb[hh * 16 + bb] = s * SCALEF;
    }
  }
}

// ======================= weight prep: WT[4][5][64c][64k] bf16 + bcat =======================
__global__ void k_wprep(
    const float* __restrict__ Wq0, const float* __restrict__ Wk0, const float* __restrict__ Wv0,
    const float* __restrict__ Ws0,
    const float* __restrict__ Wq, const float* __restrict__ Wk, const float* __restrict__ Wv,
    const float* __restrict__ Ws, const float* __restrict__ Wqt,
    const float* __restrict__ bq0, const float* __restrict__ bk0, const float* __restrict__ bv0,
    const float* __restrict__ bs0,
    const float* __restrict__ bq, const float* __restrict__ bk, const float* __restrict__ bv,
    const float* __restrict__ bs, const float* __restrict__ bqt,
    unsigned short* __restrict__ WT, float* __restrict__ bcat) {
  const int id = blockIdx.x * 256 + threadIdx.x;
  if (id >= 4 * 5 * 4096) return;
  const int l = id / 20480;
  const int rem = id - l * 20480;
  const int mat = rem >> 12;
  const int idx = rem & 4095;
  const int k = idx >> 6;
  const int c = idx & 63;
  float v;
  if (mat == 0)      v = (l == 0) ? Wq0[idx] : Wq[(l - 1) * 4096 + idx];
  else if (mat == 1) v = (l == 0) ? Wk0[idx] : Wk[(l - 1) * 4096 + idx];
  else if (mat == 2) v = (l == 0) ? Wv0[idx] : Wv[(l - 1) * 4096 + idx];
  else if (mat == 3) v = (l == 0) ? Ws0[idx] : Ws[(l - 1) * 4096 + idx];
  else               v = Wqt[l * 4096 + idx];
  WT[(size_t)(l * 5 + mat) * 4096 + c * 64 + k] = f2bf(v);
  if (k == 0) {
    float b;
    if (mat == 0)      b = (l == 0) ? bq0[c] : bq[(l - 1) * 64 + c];
    else if (mat == 1) b = (l == 0) ? bk0[c] : bk[(l - 1) * 64 + c];
    else if (mat == 2) b = (l == 0) ? bv0[c] : bv[(l - 1) * 64 + c];
    else if (mat == 3) b = (l == 0) ? bs0[c] : bs[(l - 1) * 64 + c];
    else               b = bqt[l * 64 + c];
    bcat[(l * 5 + mat) * 64 + c] = b;
  }
}

__global__ void k_xcast(const float* __restrict__ x, unsigned short* __restrict__ xb, int n4) {
  int i = blockIdx.x * 256 + threadIdx.x;
  if (i < n4) {
    float4 v = ((const float4*)x)[i];
    ushort4 o;
    o.x = f2bf(v.x); o.y = f2bf(v.y); o.z = f2bf(v.z); o.w = f2bf(v.w);
    ((ushort4*)xb)[i] = o;
  }
}

// ======================= node linear via MFMA =======================
// One wave per 16-row tile; computes ALL 5 matrices (40 MFMA) reusing the
// A fragments. No LDS, no barrier. mats: 0=Q 1=K 2=V 3=S(f32) 4=T.
__global__ __launch_bounds__(256) void k_linm(
    const unsigned short* __restrict__ Xb, const unsigned short* __restrict__ WT,
    const float* __restrict__ bcat,
    unsigned short* __restrict__ Qb, unsigned short* __restrict__ Kb,
    unsigned short* __restrict__ Vb, float* __restrict__ S,
    unsigned short* __restrict__ Tb, int n) {
  const int lane = threadIdx.x & 63;
  const int tile = blockIdx.x * 4 + (threadIdx.x >> 6);
  const int ntr = n >> 4;                    // N % 16 == 0
  if (tile >= ntr) return;
  const int r0 = tile << 4;
  const int c15 = lane & 15;
  const int kg = lane >> 4;                  // 0..3
  const int rbase = r0 + kg * 4;

  const unsigned short* xrow = Xb + (size_t)(r0 + c15) * 64 + kg * 8;
  const short8 a0 = *(const short8*)(xrow);
  const short8 a1 = *(const short8*)(xrow + 32);

  #pragma unroll
  for (int mat = 0; mat < 5; ++mat) {
    const unsigned short* wb = WT + ((size_t)mat << 12) + (size_t)c15 * 64 + kg * 8;
    f32x4 acc0 = {0.f, 0.f, 0.f, 0.f}, acc1 = acc0, acc2 = acc0, acc3 = acc0;
    {
      short8 b0 = *(const short8*)(wb);
      short8 b1 = *(const short8*)(wb + 32);
      acc0 = __builtin_amdgcn_mfma_f32_16x16x32_bf16(a0, b0, acc0, 0, 0, 0);
      acc0 = __builtin_amdgcn_mfma_f32_16x16x32_bf16(a1, b1, acc0, 0, 0, 0);
    }
    {
      short8 b0 = *(const short8*)(wb + 16 * 64);
      short8 b1 = *(const short8*)(wb + 16 * 64 + 32);
      acc1 = __builtin_amdgcn_mfma_f32_16x16x32_bf16(a0, b0, acc1, 0, 0, 0);
      acc1 = __builtin_amdgcn_mfma_f32_16x16x32_bf16(a1, b1, acc1, 0, 0, 0);
    }
    {
      short8 b0 = *(const short8*)(wb + 32 * 64);
      short8 b1 = *(const short8*)(wb + 32 * 64 + 32);
      acc2 = __builtin_amdgcn_mfma_f32_16x16x32_bf16(a0, b0, acc2, 0, 0, 0);
      acc2 = __builtin_amdgcn_mfma_f32_16x16x32_bf16(a1, b1, acc2, 0, 0, 0);
    }
    {
      short8 b0 = *(const short8*)(wb + 48 * 64);
      short8 b1 = *(const short8*)(wb + 48 * 64 + 32);
      acc3 = __builtin_amdgcn_mfma_f32_16x16x32_bf16(a0, b0, acc3, 0, 0, 0);
      acc3 = __builtin_amdgcn_mfma_f32_16x16x32_bf16(a1, b1, acc3, 0, 0, 0);
    }

    const float* bb = bcat + mat * 64;
    const float bi0 = bb[c15], bi1 = bb[16 + c15], bi2 = bb[32 + c15], bi3 = bb[48 + c15];

    if (mat == 3) {
      #pragma unroll
      for (int reg = 0; reg < 4; ++reg) {
        const size_t ro = (size_t)(rbase + reg) * 64;
        S[ro + c15]      = acc0[reg] + bi0;
        S[ro + 16 + c15] = acc1[reg] + bi1;
        S[ro + 32 + c15] = acc2[reg] + bi2;
        S[ro + 48 + c15] = acc3[reg] + bi3;
      }
    } else {
      unsigned short* O = (mat == 0) ? Qb : (mat == 1) ? Kb : (mat == 2) ? Vb : Tb;
      #pragma unroll
      for (int reg = 0; reg < 4; ++reg) {
        const size_t ro = (size_t)(rbase + reg) * 64;
        O[ro + c15]      = f2bf(acc0[reg] + bi0);
        O[ro + 16 + c15] = f2bf(acc1[reg] + bi1);
        O[ro + 32 + c15] = f2bf(acc2[reg] + bi2);
        O[ro + 48 + c15] = f2bf(acc3[reg] + bi3);
      }
    }
  }
}

// ======================= fused edge/attention kernel =======================
// Persistent waves: fixed grid, each wave loops over nodes. We/Wb hoisted to
// VGPRs once per wave. 6-deep software pipeline, named regs only.
#define LOADST(KK, VV, EE, jj) do {                                       \
    int jc_ = (jj) < mc ? (jj) : mc - 1;                                  \
    int off_ = __builtin_amdgcn_readlane(snv, jc_);                       \
    KK = *(const unsigned short*)(kbase + off_);                          \
    VV = *(const unsigned short*)(vbase + off_);                          \
    EE = eabase[(size_t)(c0 + jc_) << 4];                                 \
  } while (0)

#define COMPUTE(KK, VV, EE, jj) do {                                      \
    if ((jj) < mc) {                                                      \
      float pl = qv * bf2f(KK) + tl * EE;                                 \
      pl += __shfl_xor(pl, 1, 64);                                        \
      pl += __shfl_xor(pl, 2, 64);                                        \
      pl += __shfl_xor(pl, 4, 64);                                        \
      pl += __shfl_xor(pl, 8, 64);                                        \
      const float p = __expf(pl);                                         \
      ssum += p;                                                          \
      accv += p * bf2f(VV);                                               \
      accw += p * EE;                                                     \
    }                                                                     \
  } while (0)

__global__ __launch_bounds__(256, 6) void k_attn(
    const unsigned short* __restrict__ Qb, const unsigned short* __restrict__ Kb,
    const unsigned short* __restrict__ Vb, const unsigned short* __restrict__ Tb,
    const float* __restrict__ S, const float* __restrict__ EAp,
    const int* __restrict__ esrcp, const int* __restrict__ rowptr,
    const float* __restrict__ We, const float* __restrict__ Wb,
    unsigned short* __restrict__ Hout, int n) {
  const int t = threadIdx.x;
  const int lane = t & 63;
  const int wid = t >> 6;

  // hoisted per-layer weights (compile-time indices after unroll -> VGPRs)
  float wer[16];
  #pragma unroll
  for (int j = 0; j < 16; ++j) wer[j] = We[j * 64 + lane];
  const float wb0 = Wb[lane], wb1 = Wb[64 + lane], wb2 = Wb[128 + lane];

  const char* kbase = (const char*)Kb + 2 * lane;
  const char* vbase = (const char*)Vb + 2 * lane;
  const float* eabase = EAp + (lane & 15);

  const int stride = gridDim.x * 4;
  for (int node = blockIdx.x * 4 + wid; node < n; node += stride) {
    const float qv = bf2f(Qb[(size_t)node * 64 + lane]) * SCALEF;
    const float tl = bf2f(Tb[(size_t)node * 64 + lane]);
    const int r0 = rowptr[node], r1 = rowptr[node + 1];

    float ssum = 0.f, accv = 0.f, accw = 0.f;

    for (int c0 = r0; c0 < r1; c0 += 64) {
      const int mc = min(64, r1 - c0);
      int snv = 0;
      if (lane < mc) snv = esrcp[c0 + lane];

      unsigned short kA, vA, kB, vB, kC, vC, kD, vD, kE, vE, kF, vF;
      float eA, eB, eC, eD, eE, eF;
      LOADST(kA, vA, eA, 0);
      LOADST(kB, vB, eB, 1);
      LOADST(kC, vC, eC, 2);
      LOADST(kD, vD, eD, 3);
      LOADST(kE, vE, eE, 4);
      LOADST(kF, vF, eF, 5);

      for (int j = 0; j < mc; j += 6) {
        COMPUTE(kA, vA, eA, j);     LOADST(kA, vA, eA, j + 6);
        COMPUTE(kB, vB, eB, j + 1); LOADST(kB, vB, eB, j + 7);
        COMPUTE(kC, vC, eC, j + 2); LOADST(kC, vC, eC, j + 8);
        COMPUTE(kD, vD, eD, j + 3); LOADST(kD, vD, eD, j + 9);
        COMPUTE(kE, vE, eE, j + 4); LOADST(kE, vE, eE, j + 10);
        COMPUTE(kF, vF, eF, j + 5); LOADST(kF, vF, eF, j + 11);
      }
    }

    float agg = accv;
    #pragma unroll
    for (int j = 0; j < 16; ++j) {
      const float wj = __shfl(accw, (lane & 48) | j, 64);
      agg += wj * wer[j];
    }
    agg /= (ssum + 1e-16f);

    const float sk = S[(size_t)node * 64 + lane];
    float contrib = agg * wb0 + sk * wb1 + (agg - sk) * wb2;
    #pragma unroll
    for (int off = 1; off < 64; off <<= 1) contrib += __shfl_xor(contrib, off, 64);
    const float beta = 1.f / (1.f + __expf(-contrib));
    const float o = beta * sk + (1.f - beta) * agg;
    Hout[(size_t)node * 64 + lane] = f2bf(fmaxf(o, 0.f));
  }
}

// ======================= pooling (H bf16) =======================
__global__ __launch_bounds__(256) void k_pool(const unsigned short* __restrict__ Hf,
    const int* __restrict__ batch,
    float* __restrict__ gmax, float* __restrict__ gmean, int n) {
  const int g = blockIdx.x;
  const int lane = threadIdx.x & 63;
  const int w = threadIdx.x >> 6;

  int a = 0, b = n;
  while (a < b) { int mid = (a + b) >> 1; if (batch[mid] < g) a = mid + 1; else b = mid; }
  const int lo = a;
  b = n;
  while (a < b) { int mid = (a + b) >> 1; if (batch[mid] < g + 1) a = mid + 1; else b = mid; }
  const int hi = a;

  float vmax = -1e30f, vsum = 0.f;
  for (int i = lo + w; i < hi; i += 4) {
    const float v = bf2f(Hf[(size_t)i * 64 + lane]);
    vmax = fmaxf(vmax, v);
    vsum += v;
  }
  __shared__ float smax[4][64], ssum[4][64];
  smax[w][lane] = vmax;
  ssum[w][lane] = vsum;
  __syncthreads();
  if (w == 0) {
    const float mx = fmaxf(fmaxf(smax[0][lane], smax[1][lane]),
                           fmaxf(smax[2][lane], smax[3][lane]));
    const float sm = ssum[0][lane] + ssum[1][lane] + ssum[2][lane] + ssum[3][lane];
    const int cnt = hi - lo;
    gmax[g * 64 + lane]  = (cnt > 0) ? mx : 0.f;
    gmean[g * 64 + lane] = sm / fmaxf((float)cnt, 1.f);
  }
}

// ======================= final MLP =======================
__global__ __launch_bounds__(256) void k_mlp(const float* __restrict__ gmax,
    const float* __restrict__ gmean,
    const float* __restrict__ Wlin, const float* __restrict__ blin,
    const float* __restrict__ Wout, const float* __restrict__ bout,
    float* __restrict__ out, int G) {
  __shared__ float cat[128];
  __shared__ float red[4];
  const int g = blockIdx.x;
  const int t = threadIdx.x;
  if (t < 64) cat[t] = gmax[g * 64 + t];
  else if (t < 128) cat[t] = gmean[g * 64 + (t - 64)];
  __syncthreads();
  float acc = blin[t];
  for (int j = 0; j < 128; ++j) acc += cat[j] * Wlin[j * 256 + t];
  float p = acc * Wout[t];
  #pragma unroll
  for (int off = 1; off < 64; off <<= 1) p += __shfl_xor(p, off, 64);
  if ((t & 63) == 0) red[t >> 6] = p;
  __syncthreads();
  if (t == 0) {
    const float z = red[0] + red[1] + red[2] + red[3] + bout[0];
    out[g] = 1.f / (1.f + __expf(-z));
  }
}

// ======================= launcher =======================
extern "C" void kernel_launch(void* const* d_in, const int* in_sizes, int n_in,
                              void* d_out, int out_size, void* d_ws, size_t ws_size,
                              hipStream_t stream) {
  const float* x     = (const float*)d_in[0];
  const float* ea    = (const float*)d_in[1];
  const int*   eidx  = (const int*)d_in[2];
  const int*   batch = (const int*)d_in[3];
  const float *Wq0 = (const float*)d_in[4],  *bq0 = (const float*)d_in[5];
  const float *Wk0 = (const float*)d_in[6],  *bk0 = (const float*)d_in[7];
  const float *Wv0 = (const float*)d_in[8],  *bv0 = (const float*)d_in[9];
  const float *We0 = (const float*)d_in[10];
  const float *Ws0 = (const float*)d_in[11], *bs0 = (const float*)d_in[12];
  const float *Wb0 = (const float*)d_in[13];
  const float *Wq  = (const float*)d_in[14], *bq  = (const float*)d_in[15];
  const float *Wk  = (const float*)d_in[16], *bk  = (const float*)d_in[17];
  const float *Wv  = (const float*)d_in[18], *bv  = (const float*)d_in[19];
  const float *We  = (const float*)d_in[20];
  const float *Ws  = (const float*)d_in[21], *bs  = (const float*)d_in[22];
  const float *Wb  = (const float*)d_in[23];
  const float *Wlin = (const float*)d_in[24], *blin = (const float*)d_in[25];
  const float *Wout = (const float*)d_in[26], *bout = (const float*)d_in[27];

  const int N = in_sizes[0] / 64;
  const int E = in_sizes[2] / 2;
  const int G = out_size;
  const int* esrc = eidx;
  const int* edst = eidx + E;

  // ---- workspace carve ----
  char* wsp = (char*)d_ws;
  auto alloc = [&](size_t bytes) -> void* {
    void* p = (void*)wsp;
    wsp += (bytes + 255) & ~(size_t)255;
    return p;
  };
  unsigned short* Qb = (unsigned short*)alloc((size_t)N * 64 * 2);
  unsigned short* Kb = (unsigned short*)alloc((size_t)N * 64 * 2);
  unsigned short* Vb = (unsigned short*)alloc((size_t)N * 64 * 2);
  unsigned short* Tb = (unsigned short*)alloc((size_t)N * 64 * 2);
  float* Sb = (float*)alloc((size_t)N * 64 * 4);
  unsigned short* Hb16 = (unsigned short*)alloc((size_t)N * 64 * 2);
  unsigned short* Xb16 = (unsigned short*)alloc((size_t)N * 64 * 2);
  int* counts  = (int*)alloc((size_t)N * 4);
  int* rowptr  = (int*)alloc((size_t)(N + 1) * 4);
  int* cursor  = (int*)alloc((size_t)N * 4);
  int* colidx  = (int*)alloc((size_t)E * 4);
  int* bsums   = (int*)alloc(1024 * 4);
  int* esrcp   = (int*)alloc((size_t)E * 4);
  float* EAp   = (float*)alloc((size_t)E * 64);
  float* Wqt   = (float*)alloc(4 * 4096 * 4);
  float* bqt   = (float*)alloc(4 * 64 * 4);
  unsigned short* WT = (unsigned short*)alloc(4 * 5 * 4096 * 2);
  float* bcat  = (float*)alloc(4 * 5 * 64 * 4);
  float* gmaxf  = (float*)alloc((size_t)G * 64 * 4);
  float* gmeanf = (float*)alloc((size_t)G * 64 * 4);

  // ---- CSR build + weight prep ----
  const int gridE = (E + 255) / 256;
  const int NB1 = (N + 1023) / 1024;
  hipMemsetAsync(counts, 0, (size_t)N * 4, stream);
  k_hist<<<gridE, 256, 0, stream>>>(edst, counts, E);
  k_scan1<<<NB1, 1024, 0, stream>>>(counts, rowptr, bsums, N);
  k_scan2<<<1, 64, 0, stream>>>(bsums, NB1);
  k_scan3<<<NB1, 1024, 0, stream>>>(rowptr, cursor, bsums, N, E);
  k_scatter<<<gridE, 256, 0, stream>>>(edst, cursor, colidx, E);
  k_perm<<<gridE, 256, 0, stream>>>(colidx, esrc, ea, esrcp, EAp, E);
  k_wqt<<<4, 256, 0, stream>>>(Wq0, bq0, We0, Wq, bq, We, Wqt, bqt);
  k_wprep<<<(4 * 5 * 4096 + 255) / 256, 256, 0, stream>>>(
      Wq0, Wk0, Wv0, Ws0, Wq, Wk, Wv, Ws, Wqt,
      bq0, bk0, bv0, bs0, bq, bk, bv, bs, bqt, WT, bcat);
  k_xcast<<<(N * 16 + 255) / 256, 256, 0, stream>>>(x, Xb16, N * 16);

  // ---- 4 TransformerConv layers ----
  const int gridLinM = ((N >> 4) + 3) / 4;
  int gridAttn = (N + 3) / 4;
  if (gridAttn > 1536) gridAttn = 1536;
  for (int l = 0; l < 4; ++l) {
    const float* we_ = (l == 0) ? We0 : We + (l - 1) * 1024;
    const float* wb_ = (l == 0) ? Wb0 : Wb + (l - 1) * 192;
    const unsigned short* xin = (l == 0) ? Xb16 : Hb16;
    k_linm<<<gridLinM, 256, 0, stream>>>(xin, WT + (size_t)l * 20480, bcat + l * 320,
                                         Qb, Kb, Vb, Sb, Tb, N);
    k_attn<<<gridAttn, 256, 0, stream>>>(Qb, Kb, Vb, Tb, Sb, EAp, esrcp, rowptr,
                                         we_, wb_, Hb16, N);
  }

  // ---- pooling + MLP ----
  k_pool<<<G, 256, 0, stream>>>(Hb16, batch, gmaxf, gmeanf, N);
  k_mlp<<<G, 256, 0, stream>>>(gmaxf, gmeanf, Wlin, blin, Wout, bout,
                               (float*)d_out, G);
}

// Round 10
// 408.211 us; speedup vs baseline: 1.0862x; 1.0862x over previous
//
#include <hip/hip_runtime.h>
#include <math.h>

#define SCALEF 0.25f   // 1/sqrt(D=16)

typedef __attribute__((ext_vector_type(8))) short short8;
typedef __attribute__((ext_vector_type(4))) float f32x4;

__device__ __forceinline__ unsigned short f2bf(float x) {
  unsigned u = __float_as_uint(x);
  unsigned r = u + 0x7FFFu + ((u >> 16) & 1u);
  return (unsigned short)(r >> 16);
}
__device__ __forceinline__ float bf2f(unsigned short h) {
  return __uint_as_float(((unsigned)h) << 16);
}

// ======================= CSR build =======================
__global__ void k_hist(const int* __restrict__ dst, int* __restrict__ counts, int E) {
  int i = blockIdx.x * 256 + threadIdx.x;
  if (i < E) atomicAdd(&counts[dst[i]], 1);
}

__global__ __launch_bounds__(1024) void k_scan1(const int* __restrict__ counts,
                                                int* __restrict__ excl,
                                                int* __restrict__ bsums, int n) {
  __shared__ int sd[1024];
  int t = threadIdx.x;
  int i = blockIdx.x * 1024 + t;
  int v = (i < n) ? counts[i] : 0;
  sd[t] = v;
  __syncthreads();
  for (int off = 1; off < 1024; off <<= 1) {
    int x = (t >= off) ? sd[t - off] : 0;
    __syncthreads();
    sd[t] += x;
    __syncthreads();
  }
  if (i < n) excl[i] = sd[t] - v;
  if (t == 1023) bsums[blockIdx.x] = sd[1023];
}

__global__ void k_scan2(int* bsums, int nb) {
  if (threadIdx.x == 0 && blockIdx.x == 0) {
    int run = 0;
    for (int i = 0; i < nb; ++i) { int v = bsums[i]; bsums[i] = run; run += v; }
  }
}

__global__ __launch_bounds__(1024) void k_scan3(int* __restrict__ rowptr, int* __restrict__ cursor,
                                                const int* __restrict__ bsums, int n, int Etot) {
  int i = blockIdx.x * 1024 + threadIdx.x;
  if (i < n) { int v = rowptr[i] + bsums[blockIdx.x]; rowptr[i] = v; cursor[i] = v; }
  if (i == 0) rowptr[n] = Etot;
}

__global__ void k_scatter(const int* __restrict__ dst, int* __restrict__ cursor,
                          int* __restrict__ colidx, int E) {
  int i = blockIdx.x * 256 + threadIdx.x;
  if (i < E) { int pos = atomicAdd(&cursor[dst[i]], 1); colidx[pos] = i; }
}

// permute esrc + edge_attr into CSR order. esrcp holds BYTE offsets into the
// bf16 K/V arrays (sn*128); EAp -> bf16 (attn reads 1 ushort/lane/edge).
__global__ void k_perm(const int* __restrict__ colidx, const int* __restrict__ esrc,
                       const float* __restrict__ EA, int* __restrict__ esrcp,
                       unsigned short* __restrict__ EAp, int E) {
  int r = blockIdx.x * 256 + threadIdx.x;
  if (r >= E) return;
  const int eid = colidx[r];
  esrcp[r] = esrc[eid] * 128;
  const float4* s4 = (const float4*)(EA + ((size_t)eid << 4));
  float4 a = s4[0], b = s4[1], c = s4[2], d = s4[3];
  union { unsigned short us[16]; uint4 u4[2]; } o;
  o.us[0] = f2bf(a.x); o.us[1] = f2bf(a.y); o.us[2] = f2bf(a.z); o.us[3] = f2bf(a.w);
  o.us[4] = f2bf(b.x); o.us[5] = f2bf(b.y); o.us[6] = f2bf(b.z); o.us[7] = f2bf(b.w);
  o.us[8] = f2bf(c.x); o.us[9] = f2bf(c.y); o.us[10] = f2bf(c.z); o.us[11] = f2bf(c.w);
  o.us[12] = f2bf(d.x); o.us[13] = f2bf(d.y); o.us[14] = f2bf(d.z); o.us[15] = f2bf(d.w);
  uint4* d4 = (uint4*)(EAp + ((size_t)r << 4));
  d4[0] = o.u4[0]; d4[1] = o.u4[1];
}

// ======================= per-layer Wqt = (Wq @ M)*SCALE =======================
__global__ __launch_bounds__(256) void k_wqt(
    const float* __restrict__ Wq0, const float* __restrict__ bq0, const float* __restrict__ We0,
    const float* __restrict__ Wq, const float* __restrict__ bq, const float* __restrict__ We,
    float* __restrict__ Wqt, float* __restrict__ bqt) {
  const int l = blockIdx.x;
  const float* wq = (l == 0) ? Wq0 : Wq + (l - 1) * 4096;
  const float* bv = (l == 0) ? bq0 : bq + (l - 1) * 64;
  const float* we = (l == 0) ? We0 : We + (l - 1) * 1024;
  float* out  = Wqt + l * 4096;
  float* outb = bqt + l * 64;
  const int t = threadIdx.x;
  const int r = t >> 2;
  const int hh = t & 3;
  float wqr[16];
  #pragma unroll
  for (int d = 0; d < 16; ++d) wqr[d] = wq[r * 64 + hh * 16 + d];
  #pragma unroll
  for (int bb = 0; bb < 16; ++bb) {
    float s = 0.f;
    #pragma unroll
    for (int d = 0; d < 16; ++d) s += wqr[d] * we[bb * 64 + hh * 16 + d];
    out[r * 64 + hh * 16 + bb] = s * SCALEF;
  }
  if (r == 0) {
    #pragma unroll
    for (int bb = 0; bb < 16; ++bb) {
      float s = 0.f;
      #pragma unroll
      for (int d = 0; d < 16; ++d) s += bv[hh * 16 + d] * we[bb * 64 + hh * 16 + d];
      outb[hh * 16 + bb] = s * SCALEF;
    }
  }
}

// ======================= weight prep: WT[4][5][64c][64k] bf16 + bcat =======================
__global__ void k_wprep(
    const float* __restrict__ Wq0, const float* __restrict__ Wk0, const float* __restrict__ Wv0,
    const float* __restrict__ Ws0,
    const float* __restrict__ Wq, const float* __restrict__ Wk, const float* __restrict__ Wv,
    const float* __restrict__ Ws, const float* __restrict__ Wqt,
    const float* __restrict__ bq0, const float* __restrict__ bk0, const float* __restrict__ bv0,
    const float* __restrict__ bs0,
    const float* __restrict__ bq, const float* __restrict__ bk, const float* __restrict__ bv,
    const float* __restrict__ bs, const float* __restrict__ bqt,
    unsigned short* __restrict__ WT, float* __restrict__ bcat) {
  const int id = blockIdx.x * 256 + threadIdx.x;
  if (id >= 4 * 5 * 4096) return;
  const int l = id / 20480;
  const int rem = id - l * 20480;
  const int mat = rem >> 12;
  const int idx = rem & 4095;
  const int k = idx >> 6;
  const int c = idx & 63;
  float v;
  if (mat == 0)      v = (l == 0) ? Wq0[idx] : Wq[(l - 1) * 4096 + idx];
  else if (mat == 1) v = (l == 0) ? Wk0[idx] : Wk[(l - 1) * 4096 + idx];
  else if (mat == 2) v = (l == 0) ? Wv0[idx] : Wv[(l - 1) * 4096 + idx];
  else if (mat == 3) v = (l == 0) ? Ws0[idx] : Ws[(l - 1) * 4096 + idx];
  else               v = Wqt[l * 4096 + idx];
  WT[(size_t)(l * 5 + mat) * 4096 + c * 64 + k] = f2bf(v);
  if (k == 0) {
    float b;
    if (mat == 0)      b = (l == 0) ? bq0[c] : bq[(l - 1) * 64 + c];
    else if (mat == 1) b = (l == 0) ? bk0[c] : bk[(l - 1) * 64 + c];
    else if (mat == 2) b = (l == 0) ? bv0[c] : bv[(l - 1) * 64 + c];
    else if (mat == 3) b = (l == 0) ? bs0[c] : bs[(l - 1) * 64 + c];
    else               b = bqt[l * 64 + c];
    bcat[(l * 5 + mat) * 64 + c] = b;
  }
}

__global__ void k_xcast(const float* __restrict__ x, unsigned short* __restrict__ xb, int n4) {
  int i = blockIdx.x * 256 + threadIdx.x;
  if (i < n4) {
    float4 v = ((const float4*)x)[i];
    ushort4 o;
    o.x = f2bf(v.x); o.y = f2bf(v.y); o.z = f2bf(v.z); o.w = f2bf(v.w);
    ((ushort4*)xb)[i] = o;
  }
}

// ======================= node linear via MFMA =======================
// One wave per 16-row tile; all 5 matrices (40 MFMA) reuse the A fragments.
// All outputs bf16 now (incl. S). mats: 0=Q 1=K 2=V 3=S 4=T.
__global__ __launch_bounds__(256) void k_linm(
    const unsigned short* __restrict__ Xb, const unsigned short* __restrict__ WT,
    const float* __restrict__ bcat,
    unsigned short* __restrict__ Qb, unsigned short* __restrict__ Kb,
    unsigned short* __restrict__ Vb, unsigned short* __restrict__ Sb,
    unsigned short* __restrict__ Tb, int n) {
  const int lane = threadIdx.x & 63;
  const int tile = blockIdx.x * 4 + (threadIdx.x >> 6);
  const int ntr = n >> 4;                    // N % 16 == 0
  if (tile >= ntr) return;
  const int r0 = tile << 4;
  const int c15 = lane & 15;
  const int kg = lane >> 4;                  // 0..3
  const int rbase = r0 + kg * 4;

  const unsigned short* xrow = Xb + (size_t)(r0 + c15) * 64 + kg * 8;
  const short8 a0 = *(const short8*)(xrow);
  const short8 a1 = *(const short8*)(xrow + 32);

  #pragma unroll
  for (int mat = 0; mat < 5; ++mat) {
    const unsigned short* wb = WT + ((size_t)mat << 12) + (size_t)c15 * 64 + kg * 8;
    f32x4 acc0 = {0.f, 0.f, 0.f, 0.f}, acc1 = acc0, acc2 = acc0, acc3 = acc0;
    {
      short8 b0 = *(const short8*)(wb);
      short8 b1 = *(const short8*)(wb + 32);
      acc0 = __builtin_amdgcn_mfma_f32_16x16x32_bf16(a0, b0, acc0, 0, 0, 0);
      acc0 = __builtin_amdgcn_mfma_f32_16x16x32_bf16(a1, b1, acc0, 0, 0, 0);
    }
    {
      short8 b0 = *(const short8*)(wb + 16 * 64);
      short8 b1 = *(const short8*)(wb + 16 * 64 + 32);
      acc1 = __builtin_amdgcn_mfma_f32_16x16x32_bf16(a0, b0, acc1, 0, 0, 0);
      acc1 = __builtin_amdgcn_mfma_f32_16x16x32_bf16(a1, b1, acc1, 0, 0, 0);
    }
    {
      short8 b0 = *(const short8*)(wb + 32 * 64);
      short8 b1 = *(const short8*)(wb + 32 * 64 + 32);
      acc2 = __builtin_amdgcn_mfma_f32_16x16x32_bf16(a0, b0, acc2, 0, 0, 0);
      acc2 = __builtin_amdgcn_mfma_f32_16x16x32_bf16(a1, b1, acc2, 0, 0, 0);
    }
    {
      short8 b0 = *(const short8*)(wb + 48 * 64);
      short8 b1 = *(const short8*)(wb + 48 * 64 + 32);
      acc3 = __builtin_amdgcn_mfma_f32_16x16x32_bf16(a0, b0, acc3, 0, 0, 0);
      acc3 = __builtin_amdgcn_mfma_f32_16x16x32_bf16(a1, b1, acc3, 0, 0, 0);
    }

    const float* bb = bcat + mat * 64;
    const float bi0 = bb[c15], bi1 = bb[16 + c15], bi2 = bb[32 + c15], bi3 = bb[48 + c15];

    unsigned short* O = (mat == 0) ? Qb : (mat == 1) ? Kb : (mat == 2) ? Vb
                      : (mat == 3) ? Sb : Tb;
    #pragma unroll
    for (int reg = 0; reg < 4; ++reg) {
      const size_t ro = (size_t)(rbase + reg) * 64;
      O[ro + c15]      = f2bf(acc0[reg] + bi0);
      O[ro + 16 + c15] = f2bf(acc1[reg] + bi1);
      O[ro + 32 + c15] = f2bf(acc2[reg] + bi2);
      O[ro + 48 + c15] = f2bf(acc3[reg] + bi3);
    }
  }
}

// ======================= fused edge/attention kernel =======================
// Round-8 structure (measured best): one wave per dst node, block = 2 waves,
// no LDS, factorized logits/values, 4-deep pipeline, bf16 EA (1 ushort/lane).
#define LOADST(KK, VV, EE, jj) do {                                       \
    int jc_ = (jj) < mc ? (jj) : mc - 1;                                  \
    int off_ = __builtin_amdgcn_readlane(snv, jc_);                       \
    KK = *(const unsigned short*)(kbase + off_);                          \
    VV = *(const unsigned short*)(vbase + off_);                          \
    EE = eabase[(size_t)(c0 + jc_) << 4];                                 \
  } while (0)

#define COMPUTE(KK, VV, EE, jj) do {                                      \
    if ((jj) < mc) {                                                      \
      const float ef = bf2f(EE);                                          \
      float pl = qv * bf2f(KK) + tl * ef;                                 \
      pl += __shfl_xor(pl, 1, 64);                                        \
      pl += __shfl_xor(pl, 2, 64);                                        \
      pl += __shfl_xor(pl, 4, 64);                                        \
      pl += __shfl_xor(pl, 8, 64);                                        \
      const float p = __expf(pl);                                         \
      ssum += p;                                                          \
      accv += p * bf2f(VV);                                               \
      accw += p * ef;                                                     \
    }                                                                     \
  } while (0)

__global__ __launch_bounds__(128, 6) void k_attn(
    const unsigned short* __restrict__ Qb, const unsigned short* __restrict__ Kb,
    const unsigned short* __restrict__ Vb, const unsigned short* __restrict__ Tb,
    const unsigned short* __restrict__ Sb, const unsigned short* __restrict__ EAp,
    const int* __restrict__ esrcp, const int* __restrict__ rowptr,
    const float* __restrict__ We, const float* __restrict__ Wb,
    unsigned short* __restrict__ Hout, int n) {
  const int t = threadIdx.x;
  const int lane = t & 63;
  const int node = blockIdx.x * 2 + (t >> 6);
  if (node >= n) return;

  const float qv = bf2f(Qb[(size_t)node * 64 + lane]) * SCALEF;
  const float tl = bf2f(Tb[(size_t)node * 64 + lane]);
  const int r0 = rowptr[node], r1 = rowptr[node + 1];

  const char* kbase = (const char*)Kb + 2 * lane;
  const char* vbase = (const char*)Vb + 2 * lane;
  const unsigned short* eabase = EAp + (lane & 15);

  float ssum = 0.f, accv = 0.f, accw = 0.f;

  for (int c0 = r0; c0 < r1; c0 += 64) {
    const int mc = min(64, r1 - c0);
    int snv = 0;
    if (lane < mc) snv = esrcp[c0 + lane];

    unsigned short kA, vA, kB, vB, kC, vC, kD, vD;
    unsigned short eA, eB, eC, eD;
    LOADST(kA, vA, eA, 0);
    LOADST(kB, vB, eB, 1);
    LOADST(kC, vC, eC, 2);
    LOADST(kD, vD, eD, 3);

    for (int j = 0; j < mc; j += 4) {
      COMPUTE(kA, vA, eA, j);     LOADST(kA, vA, eA, j + 4);
      COMPUTE(kB, vB, eB, j + 1); LOADST(kB, vB, eB, j + 5);
      COMPUTE(kC, vC, eC, j + 2); LOADST(kC, vC, eC, j + 6);
      COMPUTE(kD, vD, eD, j + 3); LOADST(kD, vD, eD, j + 7);
    }
  }

  float agg = accv;
  #pragma unroll
  for (int j = 0; j < 16; ++j) {
    const float wj = __shfl(accw, (lane & 48) | j, 64);
    agg += wj * We[j * 64 + lane];
  }
  agg /= (ssum + 1e-16f);

  const float sk = bf2f(Sb[(size_t)node * 64 + lane]);
  float contrib = agg * Wb[lane] + sk * Wb[64 + lane] + (agg - sk) * Wb[128 + lane];
  #pragma unroll
  for (int off = 1; off < 64; off <<= 1) contrib += __shfl_xor(contrib, off, 64);
  const float beta = 1.f / (1.f + __expf(-contrib));
  const float o = beta * sk + (1.f - beta) * agg;
  Hout[(size_t)node * 64 + lane] = f2bf(fmaxf(o, 0.f));
}

// ======================= pooling (H bf16) =======================
__global__ __launch_bounds__(256) void k_pool(const unsigned short* __restrict__ Hf,
    const int* __restrict__ batch,
    float* __restrict__ gmax, float* __restrict__ gmean, int n) {
  const int g = blockIdx.x;
  const int lane = threadIdx.x & 63;
  const int w = threadIdx.x >> 6;

  int a = 0, b = n;
  while (a < b) { int mid = (a + b) >> 1; if (batch[mid] < g) a = mid + 1; else b = mid; }
  const int lo = a;
  b = n;
  while (a < b) { int mid = (a + b) >> 1; if (batch[mid] < g + 1) a = mid + 1; else b = mid; }
  const int hi = a;

  float vmax = -1e30f, vsum = 0.f;
  for (int i = lo + w; i < hi; i += 4) {
    const float v = bf2f(Hf[(size_t)i * 64 + lane]);
    vmax = fmaxf(vmax, v);
    vsum += v;
  }
  __shared__ float smax[4][64], ssum[4][64];
  smax[w][lane] = vmax;
  ssum[w][lane] = vsum;
  __syncthreads();
  if (w == 0) {
    const float mx = fmaxf(fmaxf(smax[0][lane], smax[1][lane]),
                           fmaxf(smax[2][lane], smax[3][lane]));
    const float sm = ssum[0][lane] + ssum[1][lane] + ssum[2][lane] + ssum[3][lane];
    const int cnt = hi - lo;
    gmax[g * 64 + lane]  = (cnt > 0) ? mx : 0.f;
    gmean[g * 64 + lane] = sm / fmaxf((float)cnt, 1.f);
  }
}

// ======================= final MLP =======================
__global__ __launch_bounds__(256) void k_mlp(const float* __restrict__ gmax,
    const float* __restrict__ gmean,
    const float* __restrict__ Wlin, const float* __restrict__ blin,
    const float* __restrict__ Wout, const float* __restrict__ bout,
    float* __restrict__ out, int G) {
  __shared__ float cat[128];
  __shared__ float red[4];
  const int g = blockIdx.x;
  const int t = threadIdx.x;
  if (t < 64) cat[t] = gmax[g * 64 + t];
  else if (t < 128) cat[t] = gmean[g * 64 + (t - 64)];
  __syncthreads();
  float acc = blin[t];
  for (int j = 0; j < 128; ++j) acc += cat[j] * Wlin[j * 256 + t];
  float p = acc * Wout[t];
  #pragma unroll
  for (int off = 1; off < 64; off <<= 1) p += __shfl_xor(p, off, 64);
  if ((t & 63) == 0) red[t >> 6] = p;
  __syncthreads();
  if (t == 0) {
    const float z = red[0] + red[1] + red[2] + red[3] + bout[0];
    out[g] = 1.f / (1.f + __expf(-z));
  }
}

// ======================= launcher =======================
extern "C" void kernel_launch(void* const* d_in, const int* in_sizes, int n_in,
                              void* d_out, int out_size, void* d_ws, size_t ws_size,
                              hipStream_t stream) {
  const float* x     = (const float*)d_in[0];
  const float* ea    = (const float*)d_in[1];
  const int*   eidx  = (const int*)d_in[2];
  const int*   batch = (const int*)d_in[3];
  const float *Wq0 = (const float*)d_in[4],  *bq0 = (const float*)d_in[5];
  const float *Wk0 = (const float*)d_in[6],  *bk0 = (const float*)d_in[7];
  const float *Wv0 = (const float*)d_in[8],  *bv0 = (const float*)d_in[9];
  const float *We0 = (const float*)d_in[10];
  const float *Ws0 = (const float*)d_in[11], *bs0 = (const float*)d_in[12];
  const float *Wb0 = (const float*)d_in[13];
  const float *Wq  = (const float*)d_in[14], *bq  = (const float*)d_in[15];
  const float *Wk  = (const float*)d_in[16], *bk  = (const float*)d_in[17];
  const float *Wv  = (const float*)d_in[18], *bv  = (const float*)d_in[19];
  const float *We  = (const float*)d_in[20];
  const float *Ws  = (const float*)d_in[21], *bs  = (const float*)d_in[22];
  const float *Wb  = (const float*)d_in[23];
  const float *Wlin = (const float*)d_in[24], *blin = (const float*)d_in[25];
  const float *Wout = (const float*)d_in[26], *bout = (const float*)d_in[27];

  const int N = in_sizes[0] / 64;
  const int E = in_sizes[2] / 2;
  const int G = out_size;
  const int* esrc = eidx;
  const int* edst = eidx + E;

  // ---- workspace carve ----
  char* wsp = (char*)d_ws;
  auto alloc = [&](size_t bytes) -> void* {
    void* p = (void*)wsp;
    wsp += (bytes + 255) & ~(size_t)255;
    return p;
  };
  unsigned short* Qb = (unsigned short*)alloc((size_t)N * 64 * 2);
  unsigned short* Kb = (unsigned short*)alloc((size_t)N * 64 * 2);
  unsigned short* Vb = (unsigned short*)alloc((size_t)N * 64 * 2);
  unsigned short* Tb = (unsigned short*)alloc((size_t)N * 64 * 2);
  unsigned short* Sb16 = (unsigned short*)alloc((size_t)N * 64 * 2);
  unsigned short* Hb16 = (unsigned short*)alloc((size_t)N * 64 * 2);
  unsigned short* Xb16 = (unsigned short*)alloc((size_t)N * 64 * 2);
  int* counts  = (int*)alloc((size_t)N * 4);
  int* rowptr  = (int*)alloc((size_t)(N + 1) * 4);
  int* cursor  = (int*)alloc((size_t)N * 4);
  int* colidx  = (int*)alloc((size_t)E * 4);
  int* bsums   = (int*)alloc(1024 * 4);
  int* esrcp   = (int*)alloc((size_t)E * 4);
  unsigned short* EAp = (unsigned short*)alloc((size_t)E * 16 * 2);
  float* Wqt   = (float*)alloc(4 * 4096 * 4);
  float* bqt   = (float*)alloc(4 * 64 * 4);
  unsigned short* WT = (unsigned short*)alloc(4 * 5 * 4096 * 2);
  float* bcat  = (float*)alloc(4 * 5 * 64 * 4);
  float* gmaxf  = (float*)alloc((size_t)G * 64 * 4);
  float* gmeanf = (float*)alloc((size_t)G * 64 * 4);

  // ---- CSR build + weight prep ----
  const int gridE = (E + 255) / 256;
  const int NB1 = (N + 1023) / 1024;
  hipMemsetAsync(counts, 0, (size_t)N * 4, stream);
  k_hist<<<gridE, 256, 0, stream>>>(edst, counts, E);
  k_scan1<<<NB1, 1024, 0, stream>>>(counts, rowptr, bsums, N);
  k_scan2<<<1, 64, 0, stream>>>(bsums, NB1);
  k_scan3<<<NB1, 1024, 0, stream>>>(rowptr, cursor, bsums, N, E);
  k_scatter<<<gridE, 256, 0, stream>>>(edst, cursor, colidx, E);
  k_perm<<<gridE, 256, 0, stream>>>(colidx, esrc, ea, esrcp, EAp, E);
  k_wqt<<<4, 256, 0, stream>>>(Wq0, bq0, We0, Wq, bq, We, Wqt, bqt);
  k_wprep<<<(4 * 5 * 4096 + 255) / 256, 256, 0, stream>>>(
      Wq0, Wk0, Wv0, Ws0, Wq, Wk, Wv, Ws, Wqt,
      bq0, bk0, bv0, bs0, bq, bk, bv, bs, bqt, WT, bcat);
  k_xcast<<<(N * 16 + 255) / 256, 256, 0, stream>>>(x, Xb16, N * 16);

  // ---- 4 TransformerConv layers ----
  const int gridLinM = ((N >> 4) + 3) / 4;
  const int gridAttn = (N + 1) / 2;
  for (int l = 0; l < 4; ++l) {
    const float* we_ = (l == 0) ? We0 : We + (l - 1) * 1024;
    const float* wb_ = (l == 0) ? Wb0 : Wb + (l - 1) * 192;
    const unsigned short* xin = (l == 0) ? Xb16 : Hb16;
    k_linm<<<gridLinM, 256, 0, stream>>>(xin, WT + (size_t)l * 20480, bcat + l * 320,
                                         Qb, Kb, Vb, Sb16, Tb, N);
    k_attn<<<gridAttn, 128, 0, stream>>>(Qb, Kb, Vb, Tb, Sb16, EAp, esrcp, rowptr,
                                         we_, wb_, Hb16, N);
  }

  // ---- pooling + MLP ----
  k_pool<<<G, 256, 0, stream>>>(Hb16, batch, gmaxf, gmeanf, N);
  k_mlp<<<G, 256, 0, stream>>>(gmaxf, gmeanf, Wlin, blin, Wout, bout,
                               (float*)d_out, G);
}

// Round 11
// 371.489 us; speedup vs baseline: 1.1935x; 1.0989x over previous
//
#include <hip/hip_runtime.h>
#include <math.h>

#define SCALEF 0.25f   // 1/sqrt(D=16)

typedef __attribute__((ext_vector_type(8))) short short8;
typedef __attribute__((ext_vector_type(4))) float f32x4;

__device__ __forceinline__ unsigned short f2bf(float x) {
  unsigned u = __float_as_uint(x);
  unsigned r = u + 0x7FFFu + ((u >> 16) & 1u);
  return (unsigned short)(r >> 16);
}
__device__ __forceinline__ float bf2f(unsigned short h) {
  return __uint_as_float(((unsigned)h) << 16);
}

// ======================= CSR build =======================
__global__ void k_hist(const int* __restrict__ dst, int* __restrict__ counts, int E) {
  int i = blockIdx.x * 256 + threadIdx.x;
  if (i < E) atomicAdd(&counts[dst[i]], 1);
}

__global__ __launch_bounds__(1024) void k_scan1(const int* __restrict__ counts,
                                                int* __restrict__ excl,
                                                int* __restrict__ bsums, int n) {
  __shared__ int sd[1024];
  int t = threadIdx.x;
  int i = blockIdx.x * 1024 + t;
  int v = (i < n) ? counts[i] : 0;
  sd[t] = v;
  __syncthreads();
  for (int off = 1; off < 1024; off <<= 1) {
    int x = (t >= off) ? sd[t - off] : 0;
    __syncthreads();
    sd[t] += x;
    __syncthreads();
  }
  if (i < n) excl[i] = sd[t] - v;
  if (t == 1023) bsums[blockIdx.x] = sd[1023];
}

// parallel wave-scan over <=64 block sums (was a single-thread serial loop)
__global__ __launch_bounds__(64) void k_scan2(int* bsums, int nb) {
  const int lane = threadIdx.x;
  int v = (lane < nb) ? bsums[lane] : 0;
  const int orig = v;
  for (int off = 1; off < 64; off <<= 1) {
    int u = __shfl_up(v, off, 64);
    if (lane >= off) v += u;
  }
  if (lane < nb) bsums[lane] = v - orig;   // exclusive
}

__global__ __launch_bounds__(1024) void k_scan3(int* __restrict__ rowptr, int* __restrict__ cursor,
                                                const int* __restrict__ bsums, int n, int Etot) {
  int i = blockIdx.x * 1024 + threadIdx.x;
  if (i < n) { int v = rowptr[i] + bsums[blockIdx.x]; rowptr[i] = v; cursor[i] = v; }
  if (i == 0) rowptr[n] = Etot;
}

// fused scatter+permute: place each edge directly at its CSR slot.
// esrcp holds BYTE offsets into the packed KV array (sn*256); EA -> bf16 row.
__global__ void k_scatperm(const int* __restrict__ esrc, const int* __restrict__ edst,
                           const float* __restrict__ EA, int* __restrict__ cursor,
                           int* __restrict__ esrcp, unsigned short* __restrict__ EAp, int E) {
  int i = blockIdx.x * 256 + threadIdx.x;
  if (i >= E) return;
  const int pos = atomicAdd(&cursor[edst[i]], 1);
  esrcp[pos] = esrc[i] * 256;
  const float4* s4 = (const float4*)(EA + ((size_t)i << 4));
  float4 a = s4[0], b = s4[1], c = s4[2], d = s4[3];
  union { unsigned short us[16]; uint4 u4[2]; } o;
  o.us[0] = f2bf(a.x); o.us[1] = f2bf(a.y); o.us[2] = f2bf(a.z); o.us[3] = f2bf(a.w);
  o.us[4] = f2bf(b.x); o.us[5] = f2bf(b.y); o.us[6] = f2bf(b.z); o.us[7] = f2bf(b.w);
  o.us[8] = f2bf(c.x); o.us[9] = f2bf(c.y); o.us[10] = f2bf(c.z); o.us[11] = f2bf(c.w);
  o.us[12] = f2bf(d.x); o.us[13] = f2bf(d.y); o.us[14] = f2bf(d.z); o.us[15] = f2bf(d.w);
  uint4* d4 = (uint4*)(EAp + ((size_t)pos << 4));
  d4[0] = o.u4[0]; d4[1] = o.u4[1];
}

// ======================= per-layer Wqt = (Wq @ M)*SCALE =======================
__global__ __launch_bounds__(256) void k_wqt(
    const float* __restrict__ Wq0, const float* __restrict__ bq0, const float* __restrict__ We0,
    const float* __restrict__ Wq, const float* __restrict__ bq, const float* __restrict__ We,
    float* __restrict__ Wqt, float* __restrict__ bqt) {
  const int l = blockIdx.x;
  const float* wq = (l == 0) ? Wq0 : Wq + (l - 1) * 4096;
  const float* bv = (l == 0) ? bq0 : bq + (l - 1) * 64;
  const float* we = (l == 0) ? We0 : We + (l - 1) * 1024;
  float* out  = Wqt + l * 4096;
  float* outb = bqt + l * 64;
  const int t = threadIdx.x;
  const int r = t >> 2;
  const int hh = t & 3;
  float wqr[16];
  #pragma unroll
  for (int d = 0; d < 16; ++d) wqr[d] = wq[r * 64 + hh * 16 + d];
  #pragma unroll
  for (int bb = 0; bb < 16; ++bb) {
    float s = 0.f;
    #pragma unroll
    for (int d = 0; d < 16; ++d) s += wqr[d] * we[bb * 64 + hh * 16 + d];
    out[r * 64 + hh * 16 + bb] = s * SCALEF;
  }
  if (r == 0) {
    #pragma unroll
    for (int bb = 0; bb < 16; ++bb) {
      float s = 0.f;
      #pragma unroll
      for (int d = 0; d < 16; ++d) s += bv[hh * 16 + d] * we[bb * 64 + hh * 16 + d];
      outb[hh * 16 + bb] = s * SCALEF;
    }
  }
}

// ======================= fused prep: weight transpose->bf16 + x->bf16 =======================
__global__ void k_prep(
    const float* __restrict__ x, unsigned short* __restrict__ xb, int n16,
    const float* __restrict__ Wq0, const float* __restrict__ Wk0, const float* __restrict__ Wv0,
    const float* __restrict__ Ws0,
    const float* __restrict__ Wq, const float* __restrict__ Wk, const float* __restrict__ Wv,
    const float* __restrict__ Ws, const float* __restrict__ Wqt,
    const float* __restrict__ bq0, const float* __restrict__ bk0, const float* __restrict__ bv0,
    const float* __restrict__ bs0,
    const float* __restrict__ bq, const float* __restrict__ bk, const float* __restrict__ bv,
    const float* __restrict__ bs, const float* __restrict__ bqt,
    unsigned short* __restrict__ WT, float* __restrict__ bcat) {
  const int id = blockIdx.x * 256 + threadIdx.x;
  if (id < n16) {
    float4 v = ((const float4*)x)[id];
    ushort4 o;
    o.x = f2bf(v.x); o.y = f2bf(v.y); o.z = f2bf(v.z); o.w = f2bf(v.w);
    ((ushort4*)xb)[id] = o;
  }
  if (id < 4 * 5 * 4096) {
    const int l = id / 20480;
    const int rem = id - l * 20480;
    const int mat = rem >> 12;
    const int idx = rem & 4095;
    const int k = idx >> 6;
    const int c = idx & 63;
    float v;
    if (mat == 0)      v = (l == 0) ? Wq0[idx] : Wq[(l - 1) * 4096 + idx];
    else if (mat == 1) v = (l == 0) ? Wk0[idx] : Wk[(l - 1) * 4096 + idx];
    else if (mat == 2) v = (l == 0) ? Wv0[idx] : Wv[(l - 1) * 4096 + idx];
    else if (mat == 3) v = (l == 0) ? Ws0[idx] : Ws[(l - 1) * 4096 + idx];
    else               v = Wqt[l * 4096 + idx];
    WT[(size_t)(l * 5 + mat) * 4096 + c * 64 + k] = f2bf(v);
    if (k == 0) {
      float b;
      if (mat == 0)      b = (l == 0) ? bq0[c] : bq[(l - 1) * 64 + c];
      else if (mat == 1) b = (l == 0) ? bk0[c] : bk[(l - 1) * 64 + c];
      else if (mat == 2) b = (l == 0) ? bv0[c] : bv[(l - 1) * 64 + c];
      else if (mat == 3) b = (l == 0) ? bs0[c] : bs[(l - 1) * 64 + c];
      else               b = bqt[l * 64 + c];
      bcat[(l * 5 + mat) * 64 + c] = b;
    }
  }
}

// ======================= node linear via MFMA =======================
// One wave per 16-row tile; all 5 matrices (40 MFMA) reuse the A fragments.
// K,V write interleaved into KV16 (uint per (node,col): K low / V high ushort).
// mats: 0=Q 1=K 2=V 3=S 4=T (bf16 outputs).
__global__ __launch_bounds__(256) void k_linm(
    const unsigned short* __restrict__ Xb, const unsigned short* __restrict__ WT,
    const float* __restrict__ bcat,
    unsigned short* __restrict__ Qb, unsigned short* __restrict__ KV16,
    unsigned short* __restrict__ Sb, unsigned short* __restrict__ Tb, int n) {
  const int lane = threadIdx.x & 63;
  const int tile = blockIdx.x * 4 + (threadIdx.x >> 6);
  const int ntr = n >> 4;                    // N % 16 == 0
  if (tile >= ntr) return;
  const int r0 = tile << 4;
  const int c15 = lane & 15;
  const int kg = lane >> 4;                  // 0..3
  const int rbase = r0 + kg * 4;

  const unsigned short* xrow = Xb + (size_t)(r0 + c15) * 64 + kg * 8;
  const short8 a0 = *(const short8*)(xrow);
  const short8 a1 = *(const short8*)(xrow + 32);

  #pragma unroll
  for (int mat = 0; mat < 5; ++mat) {
    const unsigned short* wb = WT + ((size_t)mat << 12) + (size_t)c15 * 64 + kg * 8;
    f32x4 acc0 = {0.f, 0.f, 0.f, 0.f}, acc1 = acc0, acc2 = acc0, acc3 = acc0;
    {
      short8 b0 = *(const short8*)(wb);
      short8 b1 = *(const short8*)(wb + 32);
      acc0 = __builtin_amdgcn_mfma_f32_16x16x32_bf16(a0, b0, acc0, 0, 0, 0);
      acc0 = __builtin_amdgcn_mfma_f32_16x16x32_bf16(a1, b1, acc0, 0, 0, 0);
    }
    {
      short8 b0 = *(const short8*)(wb + 16 * 64);
      short8 b1 = *(const short8*)(wb + 16 * 64 + 32);
      acc1 = __builtin_amdgcn_mfma_f32_16x16x32_bf16(a0, b0, acc1, 0, 0, 0);
      acc1 = __builtin_amdgcn_mfma_f32_16x16x32_bf16(a1, b1, acc1, 0, 0, 0);
    }
    {
      short8 b0 = *(const short8*)(wb + 32 * 64);
      short8 b1 = *(const short8*)(wb + 32 * 64 + 32);
      acc2 = __builtin_amdgcn_mfma_f32_16x16x32_bf16(a0, b0, acc2, 0, 0, 0);
      acc2 = __builtin_amdgcn_mfma_f32_16x16x32_bf16(a1, b1, acc2, 0, 0, 0);
    }
    {
      short8 b0 = *(const short8*)(wb + 48 * 64);
      short8 b1 = *(const short8*)(wb + 48 * 64 + 32);
      acc3 = __builtin_amdgcn_mfma_f32_16x16x32_bf16(a0, b0, acc3, 0, 0, 0);
      acc3 = __builtin_amdgcn_mfma_f32_16x16x32_bf16(a1, b1, acc3, 0, 0, 0);
    }

    const float* bb = bcat + mat * 64;
    const float bi0 = bb[c15], bi1 = bb[16 + c15], bi2 = bb[32 + c15], bi3 = bb[48 + c15];

    if (mat == 1 || mat == 2) {
      unsigned short* O = KV16 + (mat == 2 ? 1 : 0);
      #pragma unroll
      for (int reg = 0; reg < 4; ++reg) {
        const size_t ro = (size_t)(rbase + reg) * 128;
        O[ro + 2 * c15]        = f2bf(acc0[reg] + bi0);
        O[ro + 2 * (16 + c15)] = f2bf(acc1[reg] + bi1);
        O[ro + 2 * (32 + c15)] = f2bf(acc2[reg] + bi2);
        O[ro + 2 * (48 + c15)] = f2bf(acc3[reg] + bi3);
      }
    } else {
      unsigned short* O = (mat == 0) ? Qb : (mat == 3) ? Sb : Tb;
      #pragma unroll
      for (int reg = 0; reg < 4; ++reg) {
        const size_t ro = (size_t)(rbase + reg) * 64;
        O[ro + c15]      = f2bf(acc0[reg] + bi0);
        O[ro + 16 + c15] = f2bf(acc1[reg] + bi1);
        O[ro + 32 + c15] = f2bf(acc2[reg] + bi2);
        O[ro + 48 + c15] = f2bf(acc3[reg] + bi3);
      }
    }
  }
}

// ======================= fused edge/attention kernel =======================
// One wave per dst node, block = 2 waves, no LDS, factorized logits/values,
// packed KV (1 dword/lane/edge), bf16 EA, 4-deep pipeline, 8 waves/SIMD.
#define LOADST(KV, EE, jj) do {                                           \
    int jc_ = (jj) < mc ? (jj) : mc - 1;                                  \
    int off_ = __builtin_amdgcn_readlane(snv, jc_);                       \
    KV = *(const unsigned int*)(kvbase + off_);                           \
    EE = eabase[(size_t)(c0 + jc_) << 4];                                 \
  } while (0)

#define COMPUTE(KV, EE, jj) do {                                          \
    if ((jj) < mc) {                                                      \
      const float ef = bf2f(EE);                                          \
      const float kf = __uint_as_float(KV << 16);                         \
      const float vf = __uint_as_float(KV & 0xFFFF0000u);                 \
      float pl = qv * kf + tl * ef;                                       \
      pl += __shfl_xor(pl, 1, 64);                                        \
      pl += __shfl_xor(pl, 2, 64);                                        \
      pl += __shfl_xor(pl, 4, 64);                                        \
      pl += __shfl_xor(pl, 8, 64);                                        \
      const float p = __expf(pl);                                         \
      ssum += p;                                                          \
      accv += p * vf;                                                     \
      accw += p * ef;                                                     \
    }                                                                     \
  } while (0)

__global__ __launch_bounds__(128, 8) void k_attn(
    const unsigned short* __restrict__ Qb, const unsigned short* __restrict__ KV16,
    const unsigned short* __restrict__ Tb, const unsigned short* __restrict__ Sb,
    const unsigned short* __restrict__ EAp,
    const int* __restrict__ esrcp, const int* __restrict__ rowptr,
    const float* __restrict__ We, const float* __restrict__ Wb,
    unsigned short* __restrict__ Hout, int n) {
  const int t = threadIdx.x;
  const int lane = t & 63;
  const int node = blockIdx.x * 2 + (t >> 6);
  if (node >= n) return;

  const float qv = bf2f(Qb[(size_t)node * 64 + lane]) * SCALEF;
  const float tl = bf2f(Tb[(size_t)node * 64 + lane]);
  const int r0 = rowptr[node], r1 = rowptr[node + 1];

  const char* kvbase = (const char*)KV16 + 4 * lane;
  const unsigned short* eabase = EAp + (lane & 15);

  float ssum = 0.f, accv = 0.f, accw = 0.f;

  for (int c0 = r0; c0 < r1; c0 += 64) {
    const int mc = min(64, r1 - c0);
    int snv = 0;
    if (lane < mc) snv = esrcp[c0 + lane];

    unsigned int kvA, kvB, kvC, kvD;
    unsigned short eA, eB, eC, eD;
    LOADST(kvA, eA, 0);
    LOADST(kvB, eB, 1);
    LOADST(kvC, eC, 2);
    LOADST(kvD, eD, 3);

    for (int j = 0; j < mc; j += 4) {
      COMPUTE(kvA, eA, j);     LOADST(kvA, eA, j + 4);
      COMPUTE(kvB, eB, j + 1); LOADST(kvB, eB, j + 5);
      COMPUTE(kvC, eC, j + 2); LOADST(kvC, eC, j + 6);
      COMPUTE(kvD, eD, j + 3); LOADST(kvD, eD, j + 7);
    }
  }

  float agg = accv;
  #pragma unroll
  for (int j = 0; j < 16; ++j) {
    const float wj = __shfl(accw, (lane & 48) | j, 64);
    agg += wj * We[j * 64 + lane];
  }
  agg /= (ssum + 1e-16f);

  const float sk = bf2f(Sb[(size_t)node * 64 + lane]);
  float contrib = agg * Wb[lane] + sk * Wb[64 + lane] + (agg - sk) * Wb[128 + lane];
  #pragma unroll
  for (int off = 1; off < 64; off <<= 1) contrib += __shfl_xor(contrib, off, 64);
  const float beta = 1.f / (1.f + __expf(-contrib));
  const float o = beta * sk + (1.f - beta) * agg;
  Hout[(size_t)node * 64 + lane] = f2bf(fmaxf(o, 0.f));
}

// ======================= fused pooling + MLP (one block per graph) =======================
__global__ __launch_bounds__(256) void k_poolmlp(const unsigned short* __restrict__ Hf,
    const int* __restrict__ batch,
    const float* __restrict__ Wlin, const float* __restrict__ blin,
    const float* __restrict__ Wout, const float* __restrict__ bout,
    float* __restrict__ out, int n) {
  const int g = blockIdx.x;
  const int t = threadIdx.x;
  const int lane = t & 63;
  const int w = t >> 6;

  int a = 0, b = n;
  while (a < b) { int mid = (a + b) >> 1; if (batch[mid] < g) a = mid + 1; else b = mid; }
  const int lo = a;
  b = n;
  while (a < b) { int mid = (a + b) >> 1; if (batch[mid] < g + 1) a = mid + 1; else b = mid; }
  const int hi = a;

  float vmax = -1e30f, vsum = 0.f;
  for (int i = lo + w; i < hi; i += 4) {
    const float v = bf2f(Hf[(size_t)i * 64 + lane]);
    vmax = fmaxf(vmax, v);
    vsum += v;
  }
  __shared__ float smax[4][64], ssum[4][64];
  __shared__ float cat[128];
  smax[w][lane] = vmax;
  ssum[w][lane] = vsum;
  __syncthreads();
  if (w == 0) {
    const float mx = fmaxf(fmaxf(smax[0][lane], smax[1][lane]),
                           fmaxf(smax[2][lane], smax[3][lane]));
    const float sm = ssum[0][lane] + ssum[1][lane] + ssum[2][lane] + ssum[3][lane];
    const int cnt = hi - lo;
    cat[lane]      = (cnt > 0) ? mx : 0.f;
    cat[64 + lane] = sm / fmaxf((float)cnt, 1.f);
  }
  __syncthreads();

  float acc = blin[t];
  for (int j = 0; j < 128; ++j) acc += cat[j] * Wlin[j * 256 + t];
  float p = acc * Wout[t];
  #pragma unroll
  for (int off = 1; off < 64; off <<= 1) p += __shfl_xor(p, off, 64);
  __shared__ float red[4];
  if ((t & 63) == 0) red[t >> 6] = p;
  __syncthreads();
  if (t == 0) {
    const float z = red[0] + red[1] + red[2] + red[3] + bout[0];
    out[g] = 1.f / (1.f + __expf(-z));
  }
}

// ======================= launcher =======================
extern "C" void kernel_launch(void* const* d_in, const int* in_sizes, int n_in,
                              void* d_out, int out_size, void* d_ws, size_t ws_size,
                              hipStream_t stream) {
  const float* x     = (const float*)d_in[0];
  const float* ea    = (const float*)d_in[1];
  const int*   eidx  = (const int*)d_in[2];
  const int*   batch = (const int*)d_in[3];
  const float *Wq0 = (const float*)d_in[4],  *bq0 = (const float*)d_in[5];
  const float *Wk0 = (const float*)d_in[6],  *bk0 = (const float*)d_in[7];
  const float *Wv0 = (const float*)d_in[8],  *bv0 = (const float*)d_in[9];
  const float *We0 = (const float*)d_in[10];
  const float *Ws0 = (const float*)d_in[11], *bs0 = (const float*)d_in[12];
  const float *Wb0 = (const float*)d_in[13];
  const float *Wq  = (const float*)d_in[14], *bq  = (const float*)d_in[15];
  const float *Wk  = (const float*)d_in[16], *bk  = (const float*)d_in[17];
  const float *Wv  = (const float*)d_in[18], *bv  = (const float*)d_in[19];
  const float *We  = (const float*)d_in[20];
  const float *Ws  = (const float*)d_in[21], *bs  = (const float*)d_in[22];
  const float *Wb  = (const float*)d_in[23];
  const float *Wlin = (const float*)d_in[24], *blin = (const float*)d_in[25];
  const float *Wout = (const float*)d_in[26], *bout = (const float*)d_in[27];

  const int N = in_sizes[0] / 64;
  const int E = in_sizes[2] / 2;
  const int G = out_size;
  const int* esrc = eidx;
  const int* edst = eidx + E;

  // ---- workspace carve ----
  char* wsp = (char*)d_ws;
  auto alloc = [&](size_t bytes) -> void* {
    void* p = (void*)wsp;
    wsp += (bytes + 255) & ~(size_t)255;
    return p;
  };
  unsigned short* Qb = (unsigned short*)alloc((size_t)N * 64 * 2);
  unsigned short* KV16 = (unsigned short*)alloc((size_t)N * 64 * 4);   // packed K|V
  unsigned short* Tb = (unsigned short*)alloc((size_t)N * 64 * 2);
  unsigned short* Sb16 = (unsigned short*)alloc((size_t)N * 64 * 2);
  unsigned short* Hb16 = (unsigned short*)alloc((size_t)N * 64 * 2);
  unsigned short* Xb16 = (unsigned short*)alloc((size_t)N * 64 * 2);
  int* counts  = (int*)alloc((size_t)N * 4);
  int* rowptr  = (int*)alloc((size_t)(N + 1) * 4);
  int* cursor  = (int*)alloc((size_t)N * 4);
  int* bsums   = (int*)alloc(1024 * 4);
  int* esrcp   = (int*)alloc((size_t)E * 4);
  unsigned short* EAp = (unsigned short*)alloc((size_t)E * 16 * 2);
  float* Wqt   = (float*)alloc(4 * 4096 * 4);
  float* bqt   = (float*)alloc(4 * 64 * 4);
  unsigned short* WT = (unsigned short*)alloc(4 * 5 * 4096 * 2);
  float* bcat  = (float*)alloc(4 * 5 * 64 * 4);

  // ---- CSR build + weight prep ----
  const int gridE = (E + 255) / 256;
  const int NB1 = (N + 1023) / 1024;
  hipMemsetAsync(counts, 0, (size_t)N * 4, stream);
  k_hist<<<gridE, 256, 0, stream>>>(edst, counts, E);
  k_scan1<<<NB1, 1024, 0, stream>>>(counts, rowptr, bsums, N);
  k_scan2<<<1, 64, 0, stream>>>(bsums, NB1);
  k_scan3<<<NB1, 1024, 0, stream>>>(rowptr, cursor, bsums, N, E);
  k_scatperm<<<gridE, 256, 0, stream>>>(esrc, edst, ea, cursor, esrcp, EAp, E);
  k_wqt<<<4, 256, 0, stream>>>(Wq0, bq0, We0, Wq, bq, We, Wqt, bqt);
  k_prep<<<(N * 16 + 255) / 256, 256, 0, stream>>>(
      x, Xb16, N * 16,
      Wq0, Wk0, Wv0, Ws0, Wq, Wk, Wv, Ws, Wqt,
      bq0, bk0, bv0, bs0, bq, bk, bv, bs, bqt, WT, bcat);

  // ---- 4 TransformerConv layers ----
  const int gridLinM = ((N >> 4) + 3) / 4;
  const int gridAttn = (N + 1) / 2;
  for (int l = 0; l < 4; ++l) {
    const float* we_ = (l == 0) ? We0 : We + (l - 1) * 1024;
    const float* wb_ = (l == 0) ? Wb0 : Wb + (l - 1) * 192;
    const unsigned short* xin = (l == 0) ? Xb16 : Hb16;
    k_linm<<<gridLinM, 256, 0, stream>>>(xin, WT + (size_t)l * 20480, bcat + l * 320,
                                         Qb, KV16, Sb16, Tb, N);
    k_attn<<<gridAttn, 128, 0, stream>>>(Qb, KV16, Tb, Sb16, EAp, esrcp, rowptr,
                                         we_, wb_, Hb16, N);
  }

  // ---- fused pooling + MLP ----
  k_poolmlp<<<G, 256, 0, stream>>>(Hb16, batch, Wlin, blin, Wout, bout,
                                   (float*)d_out, N);
}